// Round 14
// baseline (231.329 us; speedup 1.0000x reference)
//
#include <hip/hip_runtime.h>
#include <stdint.h>

typedef float f32x4 __attribute__((ext_vector_type(4)));
typedef __bf16 bf16x8 __attribute__((ext_vector_type(8)));
typedef unsigned short u16x8 __attribute__((ext_vector_type(8)));

#define DEV __device__ __forceinline__

DEV unsigned short f2bf(float f) {
  __bf16 h = (__bf16)f;              // native HW cvt (RNE)
  unsigned short u;
  __builtin_memcpy(&u, &h, 2);
  return u;
}
DEV float b2f(unsigned short h) { return __uint_as_float(((unsigned int)h) << 16); }

DEV void gload16(const void* g, void* l) {
  __builtin_amdgcn_global_load_lds((__attribute__((address_space(1))) void*)(g),
                                   (__attribute__((address_space(3))) void*)(l), 16, 0, 0);
}

// ---------------- all casts fused: x (2M units) + 4 weights (512K units) ----
__global__ void cast_all(const float* __restrict__ x, const float* __restrict__ Wq,
                         const float* __restrict__ Wk, const float* __restrict__ Wv,
                         const float* __restrict__ Wo, unsigned short* __restrict__ xbf,
                         unsigned short* __restrict__ wqkv, unsigned short* __restrict__ wo) {
  int i = blockIdx.x * 256 + threadIdx.x;
  const float* src;
  unsigned short* dst;
  int j;
  if (i < 2097152) {
    src = x; dst = xbf; j = i;
  } else {
    int k = i - 2097152;           // 524288 units
    int sel = k >> 17; j = k & 131071;
    src = (sel == 0) ? Wq : (sel == 1) ? Wk : (sel == 2) ? Wv : Wo;
    dst = (sel < 3) ? (wqkv + (size_t)sel * 1048576) : wo;
  }
  const float4* p = (const float4*)src + (size_t)j * 2;
  float4 a = p[0], b = p[1];
  u16x8 o;
  o[0] = f2bf(a.x); o[1] = f2bf(a.y); o[2] = f2bf(a.z); o[3] = f2bf(a.w);
  o[4] = f2bf(b.x); o[5] = f2bf(b.y); o[6] = f2bf(b.z); o[7] = f2bf(b.w);
  ((u16x8*)dst)[j] = o;
}

// ---------------- bf16 GEMM, B^T layout (out[m,n] = sum_k A[m,k]*W[n,k]) ----
// 128x128 tile, BK=64, multi-block/CU implicit overlap. No XCD swizzle
// (r4/r5 A/B). A bf16 via gload_lds (r6 A/B). MODE 1 epilogue: stage output
// tile in LDS (bank-key (m^(m>>3))&7) then coalesced 1KB-chunk copy-out.
template<int MODE>
__global__ __launch_bounds__(256, 2) void gemm_bt(
    const unsigned short* __restrict__ A, const unsigned short* __restrict__ Bw,
    void* __restrict__ out0, unsigned short* __restrict__ qp,
    unsigned short* __restrict__ kp, unsigned short* __restrict__ vp,
    int K, int N, int nTn)
{
  __shared__ unsigned short sAB[2 * 128 * 64];
  unsigned short* sA = sAB;
  unsigned short* sB = sAB + 8192;
  int t = threadIdx.x, w = t >> 6, lane = t & 63, fr = lane & 15, fq = lane >> 4;
  int bid = blockIdx.x;
  int bm = bid / nTn, bn = bid % nTn;
  int wm = w >> 1, wn = w & 1;

  f32x4 acc[4][4];
  f32x4 z4 = {0.f, 0.f, 0.f, 0.f};
#pragma unroll
  for (int mi = 0; mi < 4; ++mi)
#pragma unroll
    for (int ni = 0; ni < 4; ++ni) acc[mi][ni] = z4;

  for (int k0 = 0; k0 < K; k0 += 64) {
#pragma unroll
    for (int i = 0; i < 4; ++i) {
      int p = (i * 4 + w) * 64 + lane;
      int r = p >> 3;
      int c8 = (p & 7) ^ (r & 7);  // inverse-swizzled source column-chunk
      gload16(A + (size_t)(bm * 128 + r) * K + k0 + c8 * 8, &sA[(i * 4 + w) * 512]);
      gload16(Bw + (size_t)(bn * 128 + r) * K + k0 + c8 * 8, &sB[(i * 4 + w) * 512]);
    }
    __syncthreads();
#pragma unroll
    for (int ks = 0; ks < 2; ++ks) {
      bf16x8 af[4], bg[4];
#pragma unroll
      for (int mi = 0; mi < 4; ++mi) {
        int r = wm * 64 + mi * 16 + fr;
        int c8 = (ks * 4 + fq) ^ (r & 7);
        af[mi] = *(const bf16x8*)&sA[(r * 8 + c8) * 8];
      }
#pragma unroll
      for (int ni = 0; ni < 4; ++ni) {
        int r = wn * 64 + ni * 16 + fr;
        int c8 = (ks * 4 + fq) ^ (r & 7);
        bg[ni] = *(const bf16x8*)&sB[(r * 8 + c8) * 8];
      }
#pragma unroll
      for (int mi = 0; mi < 4; ++mi)
#pragma unroll
        for (int ni = 0; ni < 4; ++ni)
          acc[mi][ni] = __builtin_amdgcn_mfma_f32_16x16x32_bf16(af[mi], bg[ni], acc[mi][ni], 0, 0, 0);
    }
    __syncthreads();
  }

  if (MODE == 0) {
    float* O = (float*)out0;
#pragma unroll
    for (int mi = 0; mi < 4; ++mi)
#pragma unroll
      for (int ni = 0; ni < 4; ++ni)
#pragma unroll
        for (int j = 0; j < 4; ++j) {
          int m = bm * 128 + wm * 64 + mi * 16 + fq * 4 + j;
          int n = bn * 128 + wn * 64 + ni * 16 + fr;
          O[(size_t)m * N + n] = acc[mi][ni][j];
        }
  } else {
    int tsel = (bn * 128) >> 10;  // 0:Q 1:K 2:V (block-uniform)
    unsigned short* base = (tsel == 0) ? qp : ((tsel == 1) ? kp : vp);
    // stage output tile [128 l][16 chunks of 8] into sAB, chunk-XOR key (ml^(ml>>3))&7
#pragma unroll
    for (int mi = 0; mi < 4; ++mi)
#pragma unroll
      for (int ni = 0; ni < 4; ++ni)
#pragma unroll
        for (int j = 0; j < 4; ++j) {
          int ml = wm * 64 + mi * 16 + fq * 4 + j;
          int nl = wn * 64 + ni * 16 + fr;
          float v = acc[mi][ni][j];
          if (tsel < 2) v = (v > 0.f) ? (v + 1.f) : __expf(v);  // elu(v)+1
          int cidx = nl >> 3;
          int key = (ml ^ (ml >> 3)) & 7;
          int cs = (cidx & 8) | ((cidx ^ key) & 7);
          sAB[ml * 128 + cs * 8 + (nl & 7)] = f2bf(v);
        }
    __syncthreads();
    int hbase = ((bn * 128) & 1023) >> 6;  // base head of this tile
#pragma unroll
    for (int i = 0; i < 8; ++i) {
      int cc = i * 256 + t;          // 0..2047
      int row = cc >> 4, c8 = cc & 15;
      int key = (row ^ (row >> 3)) & 7;
      int cs = (c8 & 8) | ((c8 ^ key) & 7);
      u16x8 val = *(const u16x8*)&sAB[row * 128 + cs * 8];
      int mg = bm * 128 + row;
      int b = mg >> 12, l = mg & 4095;
      int hh = hbase + (c8 >> 3);
      int d = (c8 & 7) * 8;
      *(u16x8*)(base + (((size_t)(b * 16 + hh)) * 4096 + l) * 64 + d) = val;
    }
  }
}

// ---------------- pass 1: per-chunk state via MFMA ---------------------------
// S_c[e][d] = sum_s v[s][e]*k[s][d], written DIRECTLY as bf16 into Spref slots
// (scan pass converts in-place to exclusive prefix). z_c[d] = sum_s k[s][d].
__global__ __launch_bounds__(256) void chunk_state(
    const unsigned short* __restrict__ kb, const unsigned short* __restrict__ vb,
    unsigned short* __restrict__ Spref, float* __restrict__ zbuf)
{
  __shared__ unsigned short kT[64 * 136];
  __shared__ unsigned short vT[64 * 136];
  int t = threadIdx.x, w = t >> 6, lane = t & 63, fr = lane & 15, fq = lane >> 4;
  int bh = blockIdx.x >> 5, c = blockIdx.x & 31;
  size_t base = ((size_t)bh * 4096 + (size_t)c * 128) * 64;

  int s = t >> 1, d0 = (t & 1) * 32;
  const unsigned short* kpp = kb + base + (size_t)s * 64 + d0;
  const unsigned short* vpp = vb + base + (size_t)s * 64 + d0;
#pragma unroll
  for (int i = 0; i < 4; ++i) {
    u16x8 kr = *(const u16x8*)(kpp + i * 8);
    u16x8 vr = *(const u16x8*)(vpp + i * 8);
#pragma unroll
    for (int j = 0; j < 8; ++j) {
      int d = d0 + i * 8 + j;
      kT[d * 136 + s] = kr[j];
      vT[d * 136 + s] = vr[j];
    }
  }
  __syncthreads();

  f32x4 acc[4];
  f32x4 z4 = {0.f, 0.f, 0.f, 0.f};
#pragma unroll
  for (int n = 0; n < 4; ++n) acc[n] = z4;
#pragma unroll
  for (int ks = 0; ks < 4; ++ks) {
    bf16x8 av = *(const bf16x8*)&vT[(w * 16 + fr) * 136 + ks * 32 + fq * 8];
#pragma unroll
    for (int n = 0; n < 4; ++n) {
      bf16x8 bk = *(const bf16x8*)&kT[(n * 16 + fr) * 136 + ks * 32 + fq * 8];
      acc[n] = __builtin_amdgcn_mfma_f32_16x16x32_bf16(av, bk, acc[n], 0, 0, 0);
    }
  }
  size_t ob = ((size_t)bh * 32 + c) * 4096;
#pragma unroll
  for (int n = 0; n < 4; ++n)
#pragma unroll
    for (int j = 0; j < 4; ++j) {
      int e = w * 16 + fq * 4 + j, dd = n * 16 + fr;
      Spref[ob + (size_t)e * 64 + dd] = f2bf(acc[n][j]);
    }
  if (t < 64) {
    float z = 0.f;
#pragma unroll
    for (int i = 0; i < 16; ++i) {
      u16x8 kr = *(const u16x8*)&kT[t * 136 + i * 8];
#pragma unroll
      for (int j = 0; j < 8; ++j) z += b2f(kr[j]);
    }
    zbuf[((size_t)bh * 32 + c) * 64 + t] = z;
  }
}

// ---------------- pass 2: IN-PLACE exclusive prefix over 32 chunks -----------
__global__ __launch_bounds__(256) void scan_all(
    unsigned short* __restrict__ Spref, const float* __restrict__ zbuf,
    float* __restrict__ zpref)
{
  if (blockIdx.x < 512) {
    int idx = blockIdx.x * 256 + threadIdx.x;   // 131072 u32 columns
    int bh = idx >> 11, i = idx & 2047;
    unsigned int* p32 = (unsigned int*)Spref;
    size_t base = (size_t)bh * 32 * 2048 + i;
    float r0 = 0.f, r1 = 0.f;
#pragma unroll
    for (int c = 0; c < 32; ++c) {
      unsigned int v = p32[base + (size_t)c * 2048];
      float v0 = b2f((unsigned short)(v & 0xFFFFu));
      float v1 = b2f((unsigned short)(v >> 16));
      p32[base + (size_t)c * 2048] =
          (unsigned int)f2bf(r0) | ((unsigned int)f2bf(r1) << 16);
      r0 += v0; r1 += v1;
    }
  } else {
    int idx = (blockIdx.x - 512) * 256 + threadIdx.x;  // 4096 sequences
    size_t base = (size_t)(idx >> 6) * 32 * 64 + (idx & 63);
    float run = 0.f;
#pragma unroll
    for (int c = 0; c < 32; ++c) {
      float v = zbuf[base + c * 64];
      zpref[base + c * 64] = run;
      run += v;
    }
  }
}

// ---------------- pass 3: per-chunk output (v2 + async staging + coal. store)
__global__ __launch_bounds__(256, 2) void chunk_out(
    const unsigned short* __restrict__ qb, const unsigned short* __restrict__ kb,
    const unsigned short* __restrict__ vb, const unsigned short* __restrict__ Spref,
    const float* __restrict__ zpref, unsigned short* __restrict__ attn)
{
  __shared__ unsigned short sq[128 * 64];   // q (swz &7); later output stage
  __shared__ unsigned short skv[128 * 64];  // k (swz &7), then v^T [64][128] (swz &15)
  __shared__ unsigned short ss[128 * 128];  // P bf16 [m][s] (swz &15)
  __shared__ unsigned short sS[80 * 64];    // state rows e=0..63, z at 64, zeros 65..79
  int t = threadIdx.x, w = t >> 6, lane = t & 63, fr = lane & 15, fq = lane >> 4;
  int bh = blockIdx.x >> 5, c = blockIdx.x & 31;
  size_t qkbase = ((size_t)bh * 4096 + (size_t)c * 128) * 64;
  size_t sbase = ((size_t)bh * 32 + c) * 4096;

  // async staging: q, k (1024 chunks each), sS rows 0..63 (512 chunks)
#pragma unroll
  for (int i = 0; i < 4; ++i) {
    int p = (i * 4 + w) * 64 + lane;
    int r = p >> 3;
    int c8 = (p & 7) ^ (r & 7);
    gload16(qb + qkbase + (size_t)r * 64 + c8 * 8, &sq[(i * 4 + w) * 512]);
    gload16(kb + qkbase + (size_t)r * 64 + c8 * 8, &skv[(i * 4 + w) * 512]);
  }
#pragma unroll
  for (int i = 0; i < 2; ++i) {
    int p = (i * 4 + w) * 64 + lane;
    int e = p >> 3;
    int c8 = (p & 7) ^ (e & 7);
    gload16(Spref + sbase + (size_t)e * 64 + c8 * 8, &sS[(i * 4 + w) * 512]);
  }

  u16x8 vreg[4];  // v chunk staged to regs early (T14-style)
#pragma unroll
  for (int i = 0; i < 4; ++i)
    vreg[i] = *(const u16x8*)(vb + qkbase + (size_t)(t * 4 + i) * 8);

  if (t < 64) sS[64 * 64 + t] = f2bf(zpref[((size_t)bh * 32 + c) * 64 + t]);
  {
    unsigned int* zz = (unsigned int*)&sS[65 * 64];
    for (int i = t; i < 480; i += 256) zz[i] = 0u;
  }
  __syncthreads();  // b1: drains gloads (vmcnt) + LDS writes (lgkm)

  int rowbase = w * 32;
  bf16x8 aq[2][2];
#pragma unroll
  for (int mi = 0; mi < 2; ++mi)
#pragma unroll
    for (int kt = 0; kt < 2; ++kt) {
      int r = rowbase + mi * 16 + fr;
      int c8 = (kt * 4 + fq) ^ (r & 7);
      aq[mi][kt] = *(const bf16x8*)&sq[(r * 8 + c8) * 8];
    }

  // swapped QK^T: accsT[mi][ni] = C[s-tile ni][m-tile mi]; lane holds
  // P[s = ni*16+fq*4+j][m = rowbase+mi*16+fr]
  f32x4 accsT[2][8];
  f32x4 z4 = {0.f, 0.f, 0.f, 0.f};
#pragma unroll
  for (int mi = 0; mi < 2; ++mi)
#pragma unroll
    for (int ni = 0; ni < 8; ++ni) accsT[mi][ni] = z4;

#pragma unroll
  for (int ni = 0; ni < 8; ++ni)
#pragma unroll
    for (int kt = 0; kt < 2; ++kt) {
      int r = ni * 16 + fr;
      int c8 = (kt * 4 + fq) ^ (r & 7);
      bf16x8 bk = *(const bf16x8*)&skv[(r * 8 + c8) * 8];
      accsT[0][ni] = __builtin_amdgcn_mfma_f32_16x16x32_bf16(bk, aq[0][kt], accsT[0][ni], 0, 0, 0);
      accsT[1][ni] = __builtin_amdgcn_mfma_f32_16x16x32_bf16(bk, aq[1][kt], accsT[1][ni], 0, 0, 0);
    }

  // in-register causal mask + rowsum (per lane: m = rowbase+mi*16+fr)
  float rs[2];
#pragma unroll
  for (int mi = 0; mi < 2; ++mi) {
    int m16 = mi * 16 + fr;        // m - rowbase
    float sum = 0.f;
#pragma unroll
    for (int ni = 0; ni < 8; ++ni)
#pragma unroll
      for (int j = 0; j < 4; ++j) {
        int s = ni * 16 + fq * 4 + j - rowbase;  // s - rowbase
        float v = (s <= m16) ? accsT[mi][ni][j] : 0.f;
        accsT[mi][ni][j] = v;
        sum += v;
      }
    sum += __shfl_xor(sum, 16, 64);
    sum += __shfl_xor(sum, 32, 64);
    rs[mi] = sum;
  }
  __syncthreads();  // b2: all waves done reading k from skv (and q from sq)

  // write v^T into skv (row e, col s; swizzle &15)
#pragma unroll
  for (int i = 0; i < 4; ++i) {
    int p = t * 4 + i, s = p >> 3, e0g = (p & 7) * 8;
#pragma unroll
    for (int j = 0; j < 8; ++j) {
      int e = e0g + j;
      skv[(e * 16 + ((s >> 3) ^ (e & 15))) * 8 + (s & 7)] = vreg[i][j];
    }
  }
  // P -> ss as packed b32 pairs: addr chunk (2ni+(fq>>1))^(m&15), off (fq&1)*4+2p
#pragma unroll
  for (int mi = 0; mi < 2; ++mi) {
    int m = rowbase + mi * 16 + fr;
#pragma unroll
    for (int ni = 0; ni < 8; ++ni)
#pragma unroll
      for (int p = 0; p < 2; ++p) {
        unsigned int pk = (unsigned int)f2bf(accsT[mi][ni][2 * p]) |
                          ((unsigned int)f2bf(accsT[mi][ni][2 * p + 1]) << 16);
        int chunk = (2 * ni + (fq >> 1)) ^ (m & 15);
        *(unsigned int*)&ss[m * 128 + chunk * 8 + (fq & 1) * 4 + 2 * p] = pk;
      }
  }
  __syncthreads();  // b3: ss ready

  f32x4 acco[2][4];
  f32x4 accd[2];
#pragma unroll
  for (int mi = 0; mi < 2; ++mi) {
    accd[mi] = z4;
#pragma unroll
    for (int ni = 0; ni < 4; ++ni) acco[mi][ni] = z4;
  }
  // inter-chunk: q @ S (+ den column from z row)
#pragma unroll
  for (int kt = 0; kt < 2; ++kt) {
#pragma unroll
    for (int ni = 0; ni < 4; ++ni) {
      int r = ni * 16 + fr;
      int c8 = (kt * 4 + fq) ^ (r & 7);
      bf16x8 bS = *(const bf16x8*)&sS[(r * 8 + c8) * 8];
      acco[0][ni] = __builtin_amdgcn_mfma_f32_16x16x32_bf16(aq[0][kt], bS, acco[0][ni], 0, 0, 0);
      acco[1][ni] = __builtin_amdgcn_mfma_f32_16x16x32_bf16(aq[1][kt], bS, acco[1][ni], 0, 0, 0);
    }
    {
      int r = 64 + fr;
      int c8 = (kt * 4 + fq) ^ (r & 7);
      bf16x8 bz = *(const bf16x8*)&sS[(r * 8 + c8) * 8];
      accd[0] = __builtin_amdgcn_mfma_f32_16x16x32_bf16(aq[0][kt], bz, accd[0], 0, 0, 0);
      accd[1] = __builtin_amdgcn_mfma_f32_16x16x32_bf16(aq[1][kt], bz, accd[1], 0, 0, 0);
    }
  }
  // intra-chunk: masked P @ v
#pragma unroll
  for (int kt = 0; kt < 4; ++kt) {
    bf16x8 am[2];
#pragma unroll
    for (int mi = 0; mi < 2; ++mi) {
      int r = rowbase + mi * 16 + fr;
      int c8 = (kt * 4 + fq) ^ (r & 15);
      am[mi] = *(const bf16x8*)&ss[(r * 16 + c8) * 8];
    }
#pragma unroll
    for (int ni = 0; ni < 4; ++ni) {
      int r = ni * 16 + fr;
      int c8 = (kt * 4 + fq) ^ (r & 15);
      bf16x8 bv = *(const bf16x8*)&skv[(r * 16 + c8) * 8];
      acco[0][ni] = __builtin_amdgcn_mfma_f32_16x16x32_bf16(am[0], bv, acco[0][ni], 0, 0, 0);
      acco[1][ni] = __builtin_amdgcn_mfma_f32_16x16x32_bf16(am[1], bv, acco[1][ni], 0, 0, 0);
    }
  }

  int b = bh >> 4, h = bh & 15;
  // stage outputs into sq (free since b2), bank-key (m^(m>>3))&7
#pragma unroll
  for (int mi = 0; mi < 2; ++mi)
#pragma unroll
    for (int j = 0; j < 4; ++j) {
      float rsj = __shfl(rs[mi], fq * 4 + j, 64);  // rowsum for m16 = fq*4+j
      float den = __shfl(accd[mi][j], (lane & 48), 64) + rsj;
      float rden = 1.f / den;
      int m = rowbase + mi * 16 + fq * 4 + j;
      int key = (m ^ (m >> 3)) & 7;
#pragma unroll
      for (int ni = 0; ni < 4; ++ni) {
        int e = ni * 16 + fr;
        float o = acco[ni >> 31][ni][j]; // placeholder avoided; real below
        o = acco[0][ni][j]; // mi==0 path handled below
        (void)o;
        float ov = ((mi == 0) ? acco[0][ni][j] : acco[1][ni][j]) * rden + 1e-12f;
        int cidx = e >> 3;
        sq[m * 64 + ((cidx ^ key) & 7) * 8 + (e & 7)] = f2bf(ov);
      }
    }
  __syncthreads();  // b4: output stage ready
  // coalesced copy-out: 1024 chunks of 16B, 8 rows (128B each) per wave-instr
#pragma unroll
  for (int i = 0; i < 4; ++i) {
    int cc = i * 256 + t;       // 0..1023
    int row = cc >> 3, c8 = cc & 7;
    int key = (row ^ (row >> 3)) & 7;
    u16x8 val = *(const u16x8*)&sq[row * 64 + ((c8 ^ key) & 7) * 8];
    *(u16x8*)(attn + ((size_t)b * 4096 + (size_t)c * 128 + row) * 1024 + h * 64 + c8 * 8) = val;
  }
}

// ---------------- host launch ------------------------------------------------
extern "C" void kernel_launch(void* const* d_in, const int* in_sizes, int n_in,
                              void* d_out, int out_size, void* d_ws, size_t ws_size,
                              hipStream_t stream) {
  (void)in_sizes; (void)n_in; (void)out_size; (void)ws_size;
  const float* x = (const float*)d_in[0];
  const float* Wq = (const float*)d_in[1];
  const float* Wk = (const float*)d_in[2];
  const float* Wv = (const float*)d_in[3];
  const float* Wo = (const float*)d_in[4];
  char* ws = (char*)d_ws;
  unsigned short* xbf  = (unsigned short*)(ws + 0);          // 33554432 B
  unsigned short* wqkv = (unsigned short*)(ws + 33554432);   // 6291456 B
  unsigned short* wo   = (unsigned short*)(ws + 39845888);   // 2097152 B
  unsigned short* q    = (unsigned short*)(ws + 41943040);   // 33554432 B
  unsigned short* k    = (unsigned short*)(ws + 75497472);   // 33554432 B
  unsigned short* v    = (unsigned short*)(ws + 109051904);  // 33554432 B
  unsigned short* attn = (unsigned short*)(ws + 142606336);  // 33554432 B
  unsigned short* Spref= (unsigned short*)(ws + 176160768);  // 16777216 B (in-place scanned)
  float* zbuf          = (float*)(ws + 192937984);           // 524288 B
  float* zpref         = (float*)(ws + 193462272);           // 524288 B

  cast_all<<<10240, 256, 0, stream>>>(x, Wq, Wk, Wv, Wo, xbf, wqkv, wo);
  gemm_bt<1><<<3072, 256, 0, stream>>>(xbf, wqkv, nullptr, q, k, v, 1024, 3072, 24);
  chunk_state<<<2048, 256, 0, stream>>>(k, v, Spref, zbuf);
  scan_all<<<528, 256, 0, stream>>>(Spref, zbuf, zpref);
  chunk_out<<<2048, 256, 0, stream>>>(q, k, v, Spref, zpref, attn);
  gemm_bt<0><<<1024, 256, 0, stream>>>(attn, wo, d_out, nullptr, nullptr, nullptr, 1024, 1024, 8);
}

// Round 15
// 227.843 us; speedup vs baseline: 1.0153x; 1.0153x over previous
//
#include <hip/hip_runtime.h>
#include <stdint.h>

typedef float f32x4 __attribute__((ext_vector_type(4)));
typedef __bf16 bf16x8 __attribute__((ext_vector_type(8)));
typedef unsigned short u16x8 __attribute__((ext_vector_type(8)));

#define DEV __device__ __forceinline__

DEV unsigned short f2bf(float f) {
  __bf16 h = (__bf16)f;              // native HW cvt (RNE)
  unsigned short u;
  __builtin_memcpy(&u, &h, 2);
  return u;
}
DEV float b2f(unsigned short h) { return __uint_as_float(((unsigned int)h) << 16); }

DEV void gload16(const void* g, void* l) {
  __builtin_amdgcn_global_load_lds((__attribute__((address_space(1))) void*)(g),
                                   (__attribute__((address_space(3))) void*)(l), 16, 0, 0);
}

// ---------------- all casts fused: x (2M units) + 4 weights (512K units) ----
__global__ void cast_all(const float* __restrict__ x, const float* __restrict__ Wq,
                         const float* __restrict__ Wk, const float* __restrict__ Wv,
                         const float* __restrict__ Wo, unsigned short* __restrict__ xbf,
                         unsigned short* __restrict__ wqkv, unsigned short* __restrict__ wo) {
  int i = blockIdx.x * 256 + threadIdx.x;
  const float* src;
  unsigned short* dst;
  int j;
  if (i < 2097152) {
    src = x; dst = xbf; j = i;
  } else {
    int k = i - 2097152;           // 524288 units
    int sel = k >> 17; j = k & 131071;
    src = (sel == 0) ? Wq : (sel == 1) ? Wk : (sel == 2) ? Wv : Wo;
    dst = (sel < 3) ? (wqkv + (size_t)sel * 1048576) : wo;
  }
  const float4* p = (const float4*)src + (size_t)j * 2;
  float4 a = p[0], b = p[1];
  u16x8 o;
  o[0] = f2bf(a.x); o[1] = f2bf(a.y); o[2] = f2bf(a.z); o[3] = f2bf(a.w);
  o[4] = f2bf(b.x); o[5] = f2bf(b.y); o[6] = f2bf(b.z); o[7] = f2bf(b.w);
  ((u16x8*)dst)[j] = o;
}

// ---------------- bf16 GEMM, B^T layout (out[m,n] = sum_k A[m,k]*W[n,k]) ----
// 128x128 tile, BK=64, multi-block/CU implicit overlap. No XCD swizzle
// (r4/r5 A/B). A bf16 via gload_lds (r6 A/B). Scalar scatter epilogue
// (r14 A/B: LDS round-trip epilogue = 104.5->112.3us regression).
template<int MODE>
__global__ __launch_bounds__(256, 2) void gemm_bt(
    const unsigned short* __restrict__ A, const unsigned short* __restrict__ Bw,
    void* __restrict__ out0, unsigned short* __restrict__ qp,
    unsigned short* __restrict__ kp, unsigned short* __restrict__ vp,
    int K, int N, int nTn)
{
  __shared__ unsigned short sA[128 * 64];
  __shared__ unsigned short sB[128 * 64];
  int t = threadIdx.x, w = t >> 6, lane = t & 63, fr = lane & 15, fq = lane >> 4;
  int bid = blockIdx.x;
  int bm = bid / nTn, bn = bid % nTn;
  int wm = w >> 1, wn = w & 1;

  f32x4 acc[4][4];
  f32x4 z4 = {0.f, 0.f, 0.f, 0.f};
#pragma unroll
  for (int mi = 0; mi < 4; ++mi)
#pragma unroll
    for (int ni = 0; ni < 4; ++ni) acc[mi][ni] = z4;

  for (int k0 = 0; k0 < K; k0 += 64) {
#pragma unroll
    for (int i = 0; i < 4; ++i) {
      int p = (i * 4 + w) * 64 + lane;
      int r = p >> 3;
      int c8 = (p & 7) ^ (r & 7);  // inverse-swizzled source column-chunk
      gload16(A + (size_t)(bm * 128 + r) * K + k0 + c8 * 8, &sA[(i * 4 + w) * 512]);
      gload16(Bw + (size_t)(bn * 128 + r) * K + k0 + c8 * 8, &sB[(i * 4 + w) * 512]);
    }
    __syncthreads();
#pragma unroll
    for (int ks = 0; ks < 2; ++ks) {
      bf16x8 af[4], bg[4];
#pragma unroll
      for (int mi = 0; mi < 4; ++mi) {
        int r = wm * 64 + mi * 16 + fr;
        int c8 = (ks * 4 + fq) ^ (r & 7);
        af[mi] = *(const bf16x8*)&sA[(r * 8 + c8) * 8];
      }
#pragma unroll
      for (int ni = 0; ni < 4; ++ni) {
        int r = wn * 64 + ni * 16 + fr;
        int c8 = (ks * 4 + fq) ^ (r & 7);
        bg[ni] = *(const bf16x8*)&sB[(r * 8 + c8) * 8];
      }
#pragma unroll
      for (int mi = 0; mi < 4; ++mi)
#pragma unroll
        for (int ni = 0; ni < 4; ++ni)
          acc[mi][ni] = __builtin_amdgcn_mfma_f32_16x16x32_bf16(af[mi], bg[ni], acc[mi][ni], 0, 0, 0);
    }
    __syncthreads();
  }

  if (MODE == 0) {
    float* O = (float*)out0;
#pragma unroll
    for (int mi = 0; mi < 4; ++mi)
#pragma unroll
      for (int ni = 0; ni < 4; ++ni)
#pragma unroll
        for (int j = 0; j < 4; ++j) {
          int m = bm * 128 + wm * 64 + mi * 16 + fq * 4 + j;
          int n = bn * 128 + wn * 64 + ni * 16 + fr;
          O[(size_t)m * N + n] = acc[mi][ni][j];
        }
  } else {
    int tsel = (bn * 128) >> 10;  // 0:Q 1:K 2:V (whole block in one tensor)
    unsigned short* base = (tsel == 0) ? qp : ((tsel == 1) ? kp : vp);
#pragma unroll
    for (int mi = 0; mi < 4; ++mi)
#pragma unroll
      for (int ni = 0; ni < 4; ++ni)
#pragma unroll
        for (int j = 0; j < 4; ++j) {
          int m = bm * 128 + wm * 64 + mi * 16 + fq * 4 + j;  // b*4096 + l
          int n = bn * 128 + wn * 64 + ni * 16 + fr;
          int col1 = n & 1023;
          int h = col1 >> 6, d = col1 & 63;
          int b = m >> 12, l = m & 4095;
          float v = acc[mi][ni][j];
          if (tsel < 2) v = (v > 0.f) ? (v + 1.f) : __expf(v);  // elu(v)+1
          base[(((size_t)(b * 16 + h)) * 4096 + l) * 64 + d] = f2bf(v);
        }
  }
}

// ---------------- pass 1: per-chunk state via MFMA ---------------------------
// S_c[e][d] = sum_s v[s][e]*k[s][d], written DIRECTLY as bf16 into Spref slots
// (scan pass converts in-place to exclusive prefix). z_c[d] = sum_s k[s][d].
__global__ __launch_bounds__(256) void chunk_state(
    const unsigned short* __restrict__ kb, const unsigned short* __restrict__ vb,
    unsigned short* __restrict__ Spref, float* __restrict__ zbuf)
{
  __shared__ unsigned short kT[64 * 136];
  __shared__ unsigned short vT[64 * 136];
  int t = threadIdx.x, w = t >> 6, lane = t & 63, fr = lane & 15, fq = lane >> 4;
  int bh = blockIdx.x >> 5, c = blockIdx.x & 31;
  size_t base = ((size_t)bh * 4096 + (size_t)c * 128) * 64;

  int s = t >> 1, d0 = (t & 1) * 32;
  const unsigned short* kpp = kb + base + (size_t)s * 64 + d0;
  const unsigned short* vpp = vb + base + (size_t)s * 64 + d0;
#pragma unroll
  for (int i = 0; i < 4; ++i) {
    u16x8 kr = *(const u16x8*)(kpp + i * 8);
    u16x8 vr = *(const u16x8*)(vpp + i * 8);
#pragma unroll
    for (int j = 0; j < 8; ++j) {
      int d = d0 + i * 8 + j;
      kT[d * 136 + s] = kr[j];
      vT[d * 136 + s] = vr[j];
    }
  }
  __syncthreads();

  f32x4 acc[4];
  f32x4 z4 = {0.f, 0.f, 0.f, 0.f};
#pragma unroll
  for (int n = 0; n < 4; ++n) acc[n] = z4;
#pragma unroll
  for (int ks = 0; ks < 4; ++ks) {
    bf16x8 av = *(const bf16x8*)&vT[(w * 16 + fr) * 136 + ks * 32 + fq * 8];
#pragma unroll
    for (int n = 0; n < 4; ++n) {
      bf16x8 bk = *(const bf16x8*)&kT[(n * 16 + fr) * 136 + ks * 32 + fq * 8];
      acc[n] = __builtin_amdgcn_mfma_f32_16x16x32_bf16(av, bk, acc[n], 0, 0, 0);
    }
  }
  size_t ob = ((size_t)bh * 32 + c) * 4096;
#pragma unroll
  for (int n = 0; n < 4; ++n)
#pragma unroll
    for (int j = 0; j < 4; ++j) {
      int e = w * 16 + fq * 4 + j, dd = n * 16 + fr;
      Spref[ob + (size_t)e * 64 + dd] = f2bf(acc[n][j]);
    }
  if (t < 64) {
    float z = 0.f;
#pragma unroll
    for (int i = 0; i < 16; ++i) {
      u16x8 kr = *(const u16x8*)&kT[t * 136 + i * 8];
#pragma unroll
      for (int j = 0; j < 8; ++j) z += b2f(kr[j]);
    }
    zbuf[((size_t)bh * 32 + c) * 64 + t] = z;
  }
}

// ---------------- pass 2: IN-PLACE exclusive prefix over 32 chunks -----------
__global__ __launch_bounds__(256) void scan_all(
    unsigned short* __restrict__ Spref, const float* __restrict__ zbuf,
    float* __restrict__ zpref)
{
  if (blockIdx.x < 512) {
    int idx = blockIdx.x * 256 + threadIdx.x;   // 131072 u32 columns
    int bh = idx >> 11, i = idx & 2047;
    unsigned int* p32 = (unsigned int*)Spref;
    size_t base = (size_t)bh * 32 * 2048 + i;
    float r0 = 0.f, r1 = 0.f;
#pragma unroll
    for (int c = 0; c < 32; ++c) {
      unsigned int v = p32[base + (size_t)c * 2048];
      float v0 = b2f((unsigned short)(v & 0xFFFFu));
      float v1 = b2f((unsigned short)(v >> 16));
      p32[base + (size_t)c * 2048] =
          (unsigned int)f2bf(r0) | ((unsigned int)f2bf(r1) << 16);
      r0 += v0; r1 += v1;
    }
  } else {
    int idx = (blockIdx.x - 512) * 256 + threadIdx.x;  // 4096 sequences
    size_t base = (size_t)(idx >> 6) * 32 * 64 + (idx & 63);
    float run = 0.f;
#pragma unroll
    for (int c = 0; c < 32; ++c) {
      float v = zbuf[base + c * 64];
      zpref[base + c * 64] = run;
      run += v;
    }
  }
}

// ---------------- pass 3: per-chunk output (v2 + async q/k/sS staging) -------
// r13 version (best measured). Staging of q,k,sS via global_load_lds with
// inverse-swizzled per-lane SOURCE + linear LDS dest. Scalar output scatter
// (r14 A/B: LDS-staged coalesced store = regression).
__global__ __launch_bounds__(256, 2) void chunk_out(
    const unsigned short* __restrict__ qb, const unsigned short* __restrict__ kb,
    const unsigned short* __restrict__ vb, const unsigned short* __restrict__ Spref,
    const float* __restrict__ zpref, unsigned short* __restrict__ attn)
{
  __shared__ unsigned short sq[128 * 64];   // q, swizzled (&7)
  __shared__ unsigned short skv[128 * 64];  // k (swz &7), then v^T [64][128] (swz &15)
  __shared__ unsigned short ss[128 * 128];  // P bf16 [m][s] (swz &15)
  __shared__ unsigned short sS[80 * 64];    // state rows e=0..63, z at 64, zeros 65..79
  int t = threadIdx.x, w = t >> 6, lane = t & 63, fr = lane & 15, fq = lane >> 4;
  int bh = blockIdx.x >> 5, c = blockIdx.x & 31;
  size_t qkbase = ((size_t)bh * 4096 + (size_t)c * 128) * 64;
  size_t sbase = ((size_t)bh * 32 + c) * 4096;

  // async staging: q, k (1024 chunks each), sS rows 0..63 (512 chunks)
#pragma unroll
  for (int i = 0; i < 4; ++i) {
    int p = (i * 4 + w) * 64 + lane;
    int r = p >> 3;
    int c8 = (p & 7) ^ (r & 7);
    gload16(qb + qkbase + (size_t)r * 64 + c8 * 8, &sq[(i * 4 + w) * 512]);
    gload16(kb + qkbase + (size_t)r * 64 + c8 * 8, &skv[(i * 4 + w) * 512]);
  }
#pragma unroll
  for (int i = 0; i < 2; ++i) {
    int p = (i * 4 + w) * 64 + lane;
    int e = p >> 3;
    int c8 = (p & 7) ^ (e & 7);
    gload16(Spref + sbase + (size_t)e * 64 + c8 * 8, &sS[(i * 4 + w) * 512]);
  }

  u16x8 vreg[4];  // v chunk staged to regs early (T14-style)
#pragma unroll
  for (int i = 0; i < 4; ++i)
    vreg[i] = *(const u16x8*)(vb + qkbase + (size_t)(t * 4 + i) * 8);

  if (t < 64) sS[64 * 64 + t] = f2bf(zpref[((size_t)bh * 32 + c) * 64 + t]);
  {
    unsigned int* zz = (unsigned int*)&sS[65 * 64];
    for (int i = t; i < 480; i += 256) zz[i] = 0u;
  }
  __syncthreads();  // b1: drains gloads (vmcnt) + LDS writes (lgkm)

  int rowbase = w * 32;
  bf16x8 aq[2][2];
#pragma unroll
  for (int mi = 0; mi < 2; ++mi)
#pragma unroll
    for (int kt = 0; kt < 2; ++kt) {
      int r = rowbase + mi * 16 + fr;
      int c8 = (kt * 4 + fq) ^ (r & 7);
      aq[mi][kt] = *(const bf16x8*)&sq[(r * 8 + c8) * 8];
    }

  // swapped QK^T: accsT[mi][ni] = C[s-tile ni][m-tile mi]; lane holds
  // P[s = ni*16+fq*4+j][m = rowbase+mi*16+fr]
  f32x4 accsT[2][8];
  f32x4 z4 = {0.f, 0.f, 0.f, 0.f};
#pragma unroll
  for (int mi = 0; mi < 2; ++mi)
#pragma unroll
    for (int ni = 0; ni < 8; ++ni) accsT[mi][ni] = z4;

#pragma unroll
  for (int ni = 0; ni < 8; ++ni)
#pragma unroll
    for (int kt = 0; kt < 2; ++kt) {
      int r = ni * 16 + fr;
      int c8 = (kt * 4 + fq) ^ (r & 7);
      bf16x8 bk = *(const bf16x8*)&skv[(r * 8 + c8) * 8];
      accsT[0][ni] = __builtin_amdgcn_mfma_f32_16x16x32_bf16(bk, aq[0][kt], accsT[0][ni], 0, 0, 0);
      accsT[1][ni] = __builtin_amdgcn_mfma_f32_16x16x32_bf16(bk, aq[1][kt], accsT[1][ni], 0, 0, 0);
    }

  // in-register causal mask + rowsum (per lane: m = rowbase+mi*16+fr)
  float rs[2];
#pragma unroll
  for (int mi = 0; mi < 2; ++mi) {
    int m16 = mi * 16 + fr;        // m - rowbase
    float sum = 0.f;
#pragma unroll
    for (int ni = 0; ni < 8; ++ni)
#pragma unroll
      for (int j = 0; j < 4; ++j) {
        int s = ni * 16 + fq * 4 + j - rowbase;  // s - rowbase
        float v = (s <= m16) ? accsT[mi][ni][j] : 0.f;
        accsT[mi][ni][j] = v;
        sum += v;
      }
    sum += __shfl_xor(sum, 16, 64);
    sum += __shfl_xor(sum, 32, 64);
    rs[mi] = sum;
  }
  __syncthreads();  // all waves done reading k from skv

  // write v^T into skv (row e, col s; swizzle &15)
#pragma unroll
  for (int i = 0; i < 4; ++i) {
    int p = t * 4 + i, s = p >> 3, e0g = (p & 7) * 8;
#pragma unroll
    for (int j = 0; j < 8; ++j) {
      int e = e0g + j;
      skv[(e * 16 + ((s >> 3) ^ (e & 15))) * 8 + (s & 7)] = vreg[i][j];
    }
  }
  // P -> ss as packed b32 pairs: addr chunk (2ni+(fq>>1))^(m&15), off (fq&1)*4+2p
#pragma unroll
  for (int mi = 0; mi < 2; ++mi) {
    int m = rowbase + mi * 16 + fr;
#pragma unroll
    for (int ni = 0; ni < 8; ++ni)
#pragma unroll
      for (int p = 0; p < 2; ++p) {
        unsigned int pk = (unsigned int)f2bf(accsT[mi][ni][2 * p]) |
                          ((unsigned int)f2bf(accsT[mi][ni][2 * p + 1]) << 16);
        int chunk = (2 * ni + (fq >> 1)) ^ (m & 15);
        *(unsigned int*)&ss[m * 128 + chunk * 8 + (fq & 1) * 4 + 2 * p] = pk;
      }
  }
  __syncthreads();

  f32x4 acco[2][4];
  f32x4 accd[2];
#pragma unroll
  for (int mi = 0; mi < 2; ++mi) {
    accd[mi] = z4;
#pragma unroll
    for (int ni = 0; ni < 4; ++ni) acco[mi][ni] = z4;
  }
  // inter-chunk: q @ S (+ den column from z row)
#pragma unroll
  for (int kt = 0; kt < 2; ++kt) {
#pragma unroll
    for (int ni = 0; ni < 4; ++ni) {
      int r = ni * 16 + fr;
      int c8 = (kt * 4 + fq) ^ (r & 7);
      bf16x8 bS = *(const bf16x8*)&sS[(r * 8 + c8) * 8];
      acco[0][ni] = __builtin_amdgcn_mfma_f32_16x16x32_bf16(aq[0][kt], bS, acco[0][ni], 0, 0, 0);
      acco[1][ni] = __builtin_amdgcn_mfma_f32_16x16x32_bf16(aq[1][kt], bS, acco[1][ni], 0, 0, 0);
    }
    {
      int r = 64 + fr;
      int c8 = (kt * 4 + fq) ^ (r & 7);
      bf16x8 bz = *(const bf16x8*)&sS[(r * 8 + c8) * 8];
      accd[0] = __builtin_amdgcn_mfma_f32_16x16x32_bf16(aq[0][kt], bz, accd[0], 0, 0, 0);
      accd[1] = __builtin_amdgcn_mfma_f32_16x16x32_bf16(aq[1][kt], bz, accd[1], 0, 0, 0);
    }
  }
  // intra-chunk: masked P @ v
#pragma unroll
  for (int kt = 0; kt < 4; ++kt) {
    bf16x8 am[2];
#pragma unroll
    for (int mi = 0; mi < 2; ++mi) {
      int r = rowbase + mi * 16 + fr;
      int c8 = (kt * 4 + fq) ^ (r & 15);
      am[mi] = *(const bf16x8*)&ss[(r * 16 + c8) * 8];
    }
#pragma unroll
    for (int ni = 0; ni < 4; ++ni) {
      int r = ni * 16 + fr;
      int c8 = (kt * 4 + fq) ^ (r & 15);
      bf16x8 bv = *(const bf16x8*)&skv[(r * 16 + c8) * 8];
      acco[0][ni] = __builtin_amdgcn_mfma_f32_16x16x32_bf16(am[0], bv, acco[0][ni], 0, 0, 0);
      acco[1][ni] = __builtin_amdgcn_mfma_f32_16x16x32_bf16(am[1], bv, acco[1][ni], 0, 0, 0);
    }
  }

  int b = bh >> 4, h = bh & 15;
#pragma unroll
  for (int mi = 0; mi < 2; ++mi)
#pragma unroll
    for (int j = 0; j < 4; ++j) {
      float rsj = __shfl(rs[mi], fq * 4 + j, 64);  // rowsum for m16 = fq*4+j
      float den = __shfl(accd[mi][j], (lane & 48), 64) + rsj;
      float rden = 1.f / den;
      int m = rowbase + mi * 16 + fq * 4 + j;
      size_t rowoff = ((size_t)b * 4096 + (size_t)c * 128 + m) * 1024 + h * 64;
#pragma unroll
      for (int ni = 0; ni < 4; ++ni) {
        int e = ni * 16 + fr;
        float o = acco[mi][ni][j] * rden + 1e-12f;
        attn[rowoff + e] = f2bf(o);
      }
    }
}

// ---------------- host launch ------------------------------------------------
extern "C" void kernel_launch(void* const* d_in, const int* in_sizes, int n_in,
                              void* d_out, int out_size, void* d_ws, size_t ws_size,
                              hipStream_t stream) {
  (void)in_sizes; (void)n_in; (void)out_size; (void)ws_size;
  const float* x = (const float*)d_in[0];
  const float* Wq = (const float*)d_in[1];
  const float* Wk = (const float*)d_in[2];
  const float* Wv = (const float*)d_in[3];
  const float* Wo = (const float*)d_in[4];
  char* ws = (char*)d_ws;
  unsigned short* xbf  = (unsigned short*)(ws + 0);          // 33554432 B
  unsigned short* wqkv = (unsigned short*)(ws + 33554432);   // 6291456 B
  unsigned short* wo   = (unsigned short*)(ws + 39845888);   // 2097152 B
  unsigned short* q    = (unsigned short*)(ws + 41943040);   // 33554432 B
  unsigned short* k    = (unsigned short*)(ws + 75497472);   // 33554432 B
  unsigned short* v    = (unsigned short*)(ws + 109051904);  // 33554432 B
  unsigned short* attn = (unsigned short*)(ws + 142606336);  // 33554432 B
  unsigned short* Spref= (unsigned short*)(ws + 176160768);  // 16777216 B (in-place scanned)
  float* zbuf          = (float*)(ws + 192937984);           // 524288 B
  float* zpref         = (float*)(ws + 193462272);           // 524288 B

  cast_all<<<10240, 256, 0, stream>>>(x, Wq, Wk, Wv, Wo, xbf, wqkv, wo);
  gemm_bt<1><<<3072, 256, 0, stream>>>(xbf, wqkv, nullptr, q, k, v, 1024, 3072, 24);
  chunk_state<<<2048, 256, 0, stream>>>(k, v, Spref, zbuf);
  scan_all<<<528, 256, 0, stream>>>(Spref, zbuf, zpref);
  chunk_out<<<2048, 256, 0, stream>>>(q, k, v, Spref, zpref, attn);
  gemm_bt<0><<<1024, 256, 0, stream>>>(attn, wo, d_out, nullptr, nullptr, nullptr, 1024, 1024, 8);
}

// Round 16
// 224.524 us; speedup vs baseline: 1.0303x; 1.0148x over previous
//
#include <hip/hip_runtime.h>
#include <stdint.h>

typedef float f32x4 __attribute__((ext_vector_type(4)));
typedef __bf16 bf16x8 __attribute__((ext_vector_type(8)));
typedef unsigned short u16x8 __attribute__((ext_vector_type(8)));

#define DEV __device__ __forceinline__

DEV unsigned short f2bf(float f) {
  __bf16 h = (__bf16)f;              // native HW cvt (RNE)
  unsigned short u;
  __builtin_memcpy(&u, &h, 2);
  return u;
}
DEV float b2f(unsigned short h) { return __uint_as_float(((unsigned int)h) << 16); }

DEV void gload16(const void* g, void* l) {
  __builtin_amdgcn_global_load_lds((__attribute__((address_space(1))) void*)(g),
                                   (__attribute__((address_space(3))) void*)(l), 16, 0, 0);
}

// ---------------- all casts fused: x (2M units) + 4 weights (512K units) ----
__global__ void cast_all(const float* __restrict__ x, const float* __restrict__ Wq,
                         const float* __restrict__ Wk, const float* __restrict__ Wv,
                         const float* __restrict__ Wo, unsigned short* __restrict__ xbf,
                         unsigned short* __restrict__ wqkv, unsigned short* __restrict__ wo) {
  int i = blockIdx.x * 256 + threadIdx.x;
  const float* src;
  unsigned short* dst;
  int j;
  if (i < 2097152) {
    src = x; dst = xbf; j = i;
  } else {
    int k = i - 2097152;           // 524288 units
    int sel = k >> 17; j = k & 131071;
    src = (sel == 0) ? Wq : (sel == 1) ? Wk : (sel == 2) ? Wv : Wo;
    dst = (sel < 3) ? (wqkv + (size_t)sel * 1048576) : wo;
  }
  const float4* p = (const float4*)src + (size_t)j * 2;
  float4 a = p[0], b = p[1];
  u16x8 o;
  o[0] = f2bf(a.x); o[1] = f2bf(a.y); o[2] = f2bf(a.z); o[3] = f2bf(a.w);
  o[4] = f2bf(b.x); o[5] = f2bf(b.y); o[6] = f2bf(b.z); o[7] = f2bf(b.w);
  ((u16x8*)dst)[j] = o;
}

// ---------------- bf16 GEMM, B^T layout (out[m,n] = sum_k A[m,k]*W[n,k]) ----
// 128x128 tile, BK=64, multi-block/CU implicit overlap. No XCD swizzle
// (r4/r5 A/B). A bf16 via gload_lds (r6 A/B). Scalar scatter epilogue
// (r14 A/B: LDS round-trip epilogue = regression).
template<int MODE>
__global__ __launch_bounds__(256, 2) void gemm_bt(
    const unsigned short* __restrict__ A, const unsigned short* __restrict__ Bw,
    void* __restrict__ out0, unsigned short* __restrict__ qp,
    unsigned short* __restrict__ kp, unsigned short* __restrict__ vp,
    int K, int N, int nTn)
{
  __shared__ unsigned short sA[128 * 64];
  __shared__ unsigned short sB[128 * 64];
  int t = threadIdx.x, w = t >> 6, lane = t & 63, fr = lane & 15, fq = lane >> 4;
  int bid = blockIdx.x;
  int bm = bid / nTn, bn = bid % nTn;
  int wm = w >> 1, wn = w & 1;

  f32x4 acc[4][4];
  f32x4 z4 = {0.f, 0.f, 0.f, 0.f};
#pragma unroll
  for (int mi = 0; mi < 4; ++mi)
#pragma unroll
    for (int ni = 0; ni < 4; ++ni) acc[mi][ni] = z4;

  for (int k0 = 0; k0 < K; k0 += 64) {
#pragma unroll
    for (int i = 0; i < 4; ++i) {
      int p = (i * 4 + w) * 64 + lane;
      int r = p >> 3;
      int c8 = (p & 7) ^ (r & 7);  // inverse-swizzled source column-chunk
      gload16(A + (size_t)(bm * 128 + r) * K + k0 + c8 * 8, &sA[(i * 4 + w) * 512]);
      gload16(Bw + (size_t)(bn * 128 + r) * K + k0 + c8 * 8, &sB[(i * 4 + w) * 512]);
    }
    __syncthreads();
#pragma unroll
    for (int ks = 0; ks < 2; ++ks) {
      bf16x8 af[4], bg[4];
#pragma unroll
      for (int mi = 0; mi < 4; ++mi) {
        int r = wm * 64 + mi * 16 + fr;
        int c8 = (ks * 4 + fq) ^ (r & 7);
        af[mi] = *(const bf16x8*)&sA[(r * 8 + c8) * 8];
      }
#pragma unroll
      for (int ni = 0; ni < 4; ++ni) {
        int r = wn * 64 + ni * 16 + fr;
        int c8 = (ks * 4 + fq) ^ (r & 7);
        bg[ni] = *(const bf16x8*)&sB[(r * 8 + c8) * 8];
      }
#pragma unroll
      for (int mi = 0; mi < 4; ++mi)
#pragma unroll
        for (int ni = 0; ni < 4; ++ni)
          acc[mi][ni] = __builtin_amdgcn_mfma_f32_16x16x32_bf16(af[mi], bg[ni], acc[mi][ni], 0, 0, 0);
    }
    __syncthreads();
  }

  if (MODE == 0) {
    float* O = (float*)out0;
#pragma unroll
    for (int mi = 0; mi < 4; ++mi)
#pragma unroll
      for (int ni = 0; ni < 4; ++ni)
#pragma unroll
        for (int j = 0; j < 4; ++j) {
          int m = bm * 128 + wm * 64 + mi * 16 + fq * 4 + j;
          int n = bn * 128 + wn * 64 + ni * 16 + fr;
          O[(size_t)m * N + n] = acc[mi][ni][j];
        }
  } else {
    int tsel = (bn * 128) >> 10;  // 0:Q 1:K 2:V (whole block in one tensor)
    unsigned short* base = (tsel == 0) ? qp : ((tsel == 1) ? kp : vp);
#pragma unroll
    for (int mi = 0; mi < 4; ++mi)
#pragma unroll
      for (int ni = 0; ni < 4; ++ni)
#pragma unroll
        for (int j = 0; j < 4; ++j) {
          int m = bm * 128 + wm * 64 + mi * 16 + fq * 4 + j;  // b*4096 + l
          int n = bn * 128 + wn * 64 + ni * 16 + fr;
          int col1 = n & 1023;
          int h = col1 >> 6, d = col1 & 63;
          int b = m >> 12, l = m & 4095;
          float v = acc[mi][ni][j];
          if (tsel < 2) v = (v > 0.f) ? (v + 1.f) : __expf(v);  // elu(v)+1
          base[(((size_t)(b * 16 + h)) * 4096 + l) * 64 + d] = f2bf(v);
        }
  }
}

// ---------------- pass 1: per-chunk state via MFMA ---------------------------
__global__ __launch_bounds__(256) void chunk_state(
    const unsigned short* __restrict__ kb, const unsigned short* __restrict__ vb,
    unsigned short* __restrict__ Spref, float* __restrict__ zbuf)
{
  __shared__ unsigned short kT[64 * 136];
  __shared__ unsigned short vT[64 * 136];
  int t = threadIdx.x, w = t >> 6, lane = t & 63, fr = lane & 15, fq = lane >> 4;
  int bh = blockIdx.x >> 5, c = blockIdx.x & 31;
  size_t base = ((size_t)bh * 4096 + (size_t)c * 128) * 64;

  int s = t >> 1, d0 = (t & 1) * 32;
  const unsigned short* kpp = kb + base + (size_t)s * 64 + d0;
  const unsigned short* vpp = vb + base + (size_t)s * 64 + d0;
#pragma unroll
  for (int i = 0; i < 4; ++i) {
    u16x8 kr = *(const u16x8*)(kpp + i * 8);
    u16x8 vr = *(const u16x8*)(vpp + i * 8);
#pragma unroll
    for (int j = 0; j < 8; ++j) {
      int d = d0 + i * 8 + j;
      kT[d * 136 + s] = kr[j];
      vT[d * 136 + s] = vr[j];
    }
  }
  __syncthreads();

  f32x4 acc[4];
  f32x4 z4 = {0.f, 0.f, 0.f, 0.f};
#pragma unroll
  for (int n = 0; n < 4; ++n) acc[n] = z4;
#pragma unroll
  for (int ks = 0; ks < 4; ++ks) {
    bf16x8 av = *(const bf16x8*)&vT[(w * 16 + fr) * 136 + ks * 32 + fq * 8];
#pragma unroll
    for (int n = 0; n < 4; ++n) {
      bf16x8 bk = *(const bf16x8*)&kT[(n * 16 + fr) * 136 + ks * 32 + fq * 8];
      acc[n] = __builtin_amdgcn_mfma_f32_16x16x32_bf16(av, bk, acc[n], 0, 0, 0);
    }
  }
  size_t ob = ((size_t)bh * 32 + c) * 4096;
#pragma unroll
  for (int n = 0; n < 4; ++n)
#pragma unroll
    for (int j = 0; j < 4; ++j) {
      int e = w * 16 + fq * 4 + j, dd = n * 16 + fr;
      Spref[ob + (size_t)e * 64 + dd] = f2bf(acc[n][j]);
    }
  if (t < 64) {
    float z = 0.f;
#pragma unroll
    for (int i = 0; i < 16; ++i) {
      u16x8 kr = *(const u16x8*)&kT[t * 136 + i * 8];
#pragma unroll
      for (int j = 0; j < 8; ++j) z += b2f(kr[j]);
    }
    zbuf[((size_t)bh * 32 + c) * 64 + t] = z;
  }
}

// ---------------- pass 2: IN-PLACE exclusive prefix over 32 chunks -----------
__global__ __launch_bounds__(256) void scan_all(
    unsigned short* __restrict__ Spref, const float* __restrict__ zbuf,
    float* __restrict__ zpref)
{
  if (blockIdx.x < 512) {
    int idx = blockIdx.x * 256 + threadIdx.x;   // 131072 u32 columns
    int bh = idx >> 11, i = idx & 2047;
    unsigned int* p32 = (unsigned int*)Spref;
    size_t base = (size_t)bh * 32 * 2048 + i;
    float r0 = 0.f, r1 = 0.f;
#pragma unroll
    for (int c = 0; c < 32; ++c) {
      unsigned int v = p32[base + (size_t)c * 2048];
      float v0 = b2f((unsigned short)(v & 0xFFFFu));
      float v1 = b2f((unsigned short)(v >> 16));
      p32[base + (size_t)c * 2048] =
          (unsigned int)f2bf(r0) | ((unsigned int)f2bf(r1) << 16);
      r0 += v0; r1 += v1;
    }
  } else {
    int idx = (blockIdx.x - 512) * 256 + threadIdx.x;  // 4096 sequences
    size_t base = (size_t)(idx >> 6) * 32 * 64 + (idx & 63);
    float run = 0.f;
#pragma unroll
    for (int c = 0; c < 32; ++c) {
      float v = zbuf[base + c * 64];
      zpref[base + c * 64] = run;
      run += v;
    }
  }
}

// ---------------- pass 3: per-chunk output (v6: 42KB LDS -> 3 blocks/CU) -----
// r13 data paths, but ss halved (two-pass P over s-halves) and aliased onto
// the dead q-staging region. LDS pool: skv 16K | sS 10K | sq<->ss 16K = 42K.
// Half-P swizzle: chunk = (sl>>3) ^ (m&7) (write == PV-read formula; 2-way max).
__global__ __launch_bounds__(256, 3) void chunk_out(
    const unsigned short* __restrict__ qb, const unsigned short* __restrict__ kb,
    const unsigned short* __restrict__ vb, const unsigned short* __restrict__ Spref,
    const float* __restrict__ zpref, unsigned short* __restrict__ attn)
{
  __shared__ unsigned short buf[21504];
  unsigned short* skv = buf;          // k (swz &7) -> v^T [64][128] (swz &15)
  unsigned short* sS  = buf + 8192;   // state rows e=0..63, z at 64, zeros 65..79
  unsigned short* squ = buf + 13312;  // q staging (swz &7), then P-half [128][64]
  int t = threadIdx.x, w = t >> 6, lane = t & 63, fr = lane & 15, fq = lane >> 4;
  int bh = blockIdx.x >> 5, c = blockIdx.x & 31;
  size_t qkbase = ((size_t)bh * 4096 + (size_t)c * 128) * 64;
  size_t sbase = ((size_t)bh * 32 + c) * 4096;

  // async staging: q, k (1024 chunks each), sS rows 0..63 (512 chunks)
#pragma unroll
  for (int i = 0; i < 4; ++i) {
    int p = (i * 4 + w) * 64 + lane;
    int r = p >> 3;
    int c8 = (p & 7) ^ (r & 7);
    gload16(qb + qkbase + (size_t)r * 64 + c8 * 8, &squ[(i * 4 + w) * 512]);
    gload16(kb + qkbase + (size_t)r * 64 + c8 * 8, &skv[(i * 4 + w) * 512]);
  }
#pragma unroll
  for (int i = 0; i < 2; ++i) {
    int p = (i * 4 + w) * 64 + lane;
    int e = p >> 3;
    int c8 = (p & 7) ^ (e & 7);
    gload16(Spref + sbase + (size_t)e * 64 + c8 * 8, &sS[(i * 4 + w) * 512]);
  }

  u16x8 vreg[4];  // v chunk staged to regs early
#pragma unroll
  for (int i = 0; i < 4; ++i)
    vreg[i] = *(const u16x8*)(vb + qkbase + (size_t)(t * 4 + i) * 8);

  if (t < 64) sS[64 * 64 + t] = f2bf(zpref[((size_t)bh * 32 + c) * 64 + t]);
  {
    unsigned int* zz = (unsigned int*)&sS[65 * 64];
    for (int i = t; i < 480; i += 256) zz[i] = 0u;
  }
  __syncthreads();  // b1: staging drained

  int rowbase = w * 32;
  bf16x8 aq[2][2];
#pragma unroll
  for (int mi = 0; mi < 2; ++mi)
#pragma unroll
    for (int kt = 0; kt < 2; ++kt) {
      int r = rowbase + mi * 16 + fr;
      int c8 = (kt * 4 + fq) ^ (r & 7);
      aq[mi][kt] = *(const bf16x8*)&squ[(r * 8 + c8) * 8];
    }

  // swapped QK^T: accsT[mi][ni] = C[s-tile ni][m-tile mi]
  f32x4 accsT[2][8];
  f32x4 z4 = {0.f, 0.f, 0.f, 0.f};
#pragma unroll
  for (int mi = 0; mi < 2; ++mi)
#pragma unroll
    for (int ni = 0; ni < 8; ++ni) accsT[mi][ni] = z4;

#pragma unroll
  for (int ni = 0; ni < 8; ++ni)
#pragma unroll
    for (int kt = 0; kt < 2; ++kt) {
      int r = ni * 16 + fr;
      int c8 = (kt * 4 + fq) ^ (r & 7);
      bf16x8 bk = *(const bf16x8*)&skv[(r * 8 + c8) * 8];
      accsT[0][ni] = __builtin_amdgcn_mfma_f32_16x16x32_bf16(bk, aq[0][kt], accsT[0][ni], 0, 0, 0);
      accsT[1][ni] = __builtin_amdgcn_mfma_f32_16x16x32_bf16(bk, aq[1][kt], accsT[1][ni], 0, 0, 0);
    }

  // in-register causal mask + rowsum
  float rs[2];
#pragma unroll
  for (int mi = 0; mi < 2; ++mi) {
    int m16 = mi * 16 + fr;
    float sum = 0.f;
#pragma unroll
    for (int ni = 0; ni < 8; ++ni)
#pragma unroll
      for (int j = 0; j < 4; ++j) {
        int s = ni * 16 + fq * 4 + j - rowbase;
        float v = (s <= m16) ? accsT[mi][ni][j] : 0.f;
        accsT[mi][ni][j] = v;
        sum += v;
      }
    sum += __shfl_xor(sum, 16, 64);
    sum += __shfl_xor(sum, 32, 64);
    rs[mi] = sum;
  }
  __syncthreads();  // b2: k reads (skv) and q reads (squ) done

  // v^T into skv (row e, col s; swz &15); P half-0 (ni 0..3) into squ
#pragma unroll
  for (int i = 0; i < 4; ++i) {
    int p = t * 4 + i, s = p >> 3, e0g = (p & 7) * 8;
#pragma unroll
    for (int j = 0; j < 8; ++j) {
      int e = e0g + j;
      skv[(e * 16 + ((s >> 3) ^ (e & 15))) * 8 + (s & 7)] = vreg[i][j];
    }
  }
#pragma unroll
  for (int mi = 0; mi < 2; ++mi) {
    int m = rowbase + mi * 16 + fr;
#pragma unroll
    for (int nl = 0; nl < 4; ++nl)
#pragma unroll
      for (int p = 0; p < 2; ++p) {
        unsigned int pk = (unsigned int)f2bf(accsT[mi][nl][2 * p]) |
                          ((unsigned int)f2bf(accsT[mi][nl][2 * p + 1]) << 16);
        int chunk = (2 * nl + (fq >> 1)) ^ (m & 7);
        *(unsigned int*)&squ[m * 64 + chunk * 8 + (fq & 1) * 4 + 2 * p] = pk;
      }
  }
  __syncthreads();  // b3: v^T + P-half0 ready

  f32x4 acco[2][4];
  f32x4 accd[2];
#pragma unroll
  for (int mi = 0; mi < 2; ++mi) {
    accd[mi] = z4;
#pragma unroll
    for (int ni = 0; ni < 4; ++ni) acco[mi][ni] = z4;
  }
  // inter-chunk: q @ S (+ den column from z row)
#pragma unroll
  for (int kt = 0; kt < 2; ++kt) {
#pragma unroll
    for (int ni = 0; ni < 4; ++ni) {
      int r = ni * 16 + fr;
      int c8 = (kt * 4 + fq) ^ (r & 7);
      bf16x8 bS = *(const bf16x8*)&sS[(r * 8 + c8) * 8];
      acco[0][ni] = __builtin_amdgcn_mfma_f32_16x16x32_bf16(aq[0][kt], bS, acco[0][ni], 0, 0, 0);
      acco[1][ni] = __builtin_amdgcn_mfma_f32_16x16x32_bf16(aq[1][kt], bS, acco[1][ni], 0, 0, 0);
    }
    {
      int r = 64 + fr;
      int c8 = (kt * 4 + fq) ^ (r & 7);
      bf16x8 bz = *(const bf16x8*)&sS[(r * 8 + c8) * 8];
      accd[0] = __builtin_amdgcn_mfma_f32_16x16x32_bf16(aq[0][kt], bz, accd[0], 0, 0, 0);
      accd[1] = __builtin_amdgcn_mfma_f32_16x16x32_bf16(aq[1][kt], bz, accd[1], 0, 0, 0);
    }
  }
  // intra-chunk PV, s-half 0 (kt 0,1)
#pragma unroll
  for (int kt = 0; kt < 2; ++kt) {
    bf16x8 am[2];
#pragma unroll
    for (int mi = 0; mi < 2; ++mi) {
      int r = rowbase + mi * 16 + fr;
      int c8 = (kt * 4 + fq) ^ (r & 7);
      am[mi] = *(const bf16x8*)&squ[r * 64 + c8 * 8];
    }
#pragma unroll
    for (int ni = 0; ni < 4; ++ni) {
      int r = ni * 16 + fr;
      int c8 = (kt * 4 + fq) ^ (r & 15);
      bf16x8 bv = *(const bf16x8*)&skv[(r * 16 + c8) * 8];
      acco[0][ni] = __builtin_amdgcn_mfma_f32_16x16x32_bf16(am[0], bv, acco[0][ni], 0, 0, 0);
      acco[1][ni] = __builtin_amdgcn_mfma_f32_16x16x32_bf16(am[1], bv, acco[1][ni], 0, 0, 0);
    }
  }
  __syncthreads();  // b4: half-0 P reads done

  // P half-1 (ni 4..7) into squ
#pragma unroll
  for (int mi = 0; mi < 2; ++mi) {
    int m = rowbase + mi * 16 + fr;
#pragma unroll
    for (int nl = 0; nl < 4; ++nl)
#pragma unroll
      for (int p = 0; p < 2; ++p) {
        unsigned int pk = (unsigned int)f2bf(accsT[mi][4 + nl][2 * p]) |
                          ((unsigned int)f2bf(accsT[mi][4 + nl][2 * p + 1]) << 16);
        int chunk = (2 * nl + (fq >> 1)) ^ (m & 7);
        *(unsigned int*)&squ[m * 64 + chunk * 8 + (fq & 1) * 4 + 2 * p] = pk;
      }
  }
  __syncthreads();  // b5: half-1 ready

  // intra-chunk PV, s-half 1 (kt 2,3 -> local ktl 0,1; v^T rows s=64+)
#pragma unroll
  for (int ktl = 0; ktl < 2; ++ktl) {
    bf16x8 am[2];
#pragma unroll
    for (int mi = 0; mi < 2; ++mi) {
      int r = rowbase + mi * 16 + fr;
      int c8 = (ktl * 4 + fq) ^ (r & 7);
      am[mi] = *(const bf16x8*)&squ[r * 64 + c8 * 8];
    }
#pragma unroll
    for (int ni = 0; ni < 4; ++ni) {
      int r = ni * 16 + fr;
      int c8 = ((2 + ktl) * 4 + fq) ^ (r & 15);
      bf16x8 bv = *(const bf16x8*)&skv[(r * 16 + c8) * 8];
      acco[0][ni] = __builtin_amdgcn_mfma_f32_16x16x32_bf16(am[0], bv, acco[0][ni], 0, 0, 0);
      acco[1][ni] = __builtin_amdgcn_mfma_f32_16x16x32_bf16(am[1], bv, acco[1][ni], 0, 0, 0);
    }
  }

  int b = bh >> 4, h = bh & 15;
#pragma unroll
  for (int mi = 0; mi < 2; ++mi)
#pragma unroll
    for (int j = 0; j < 4; ++j) {
      float rsj = __shfl(rs[mi], fq * 4 + j, 64);
      float den = __shfl(accd[mi][j], (lane & 48), 64) + rsj;
      float rden = 1.f / den;
      int m = rowbase + mi * 16 + fq * 4 + j;
      size_t rowoff = ((size_t)b * 4096 + (size_t)c * 128 + m) * 1024 + h * 64;
#pragma unroll
      for (int ni = 0; ni < 4; ++ni) {
        int e = ni * 16 + fr;
        float o = acco[mi][ni][j] * rden + 1e-12f;
        attn[rowoff + e] = f2bf(o);
      }
    }
}

// ---------------- host launch ------------------------------------------------
extern "C" void kernel_launch(void* const* d_in, const int* in_sizes, int n_in,
                              void* d_out, int out_size, void* d_ws, size_t ws_size,
                              hipStream_t stream) {
  (void)in_sizes; (void)n_in; (void)out_size; (void)ws_size;
  const float* x = (const float*)d_in[0];
  const float* Wq = (const float*)d_in[1];
  const float* Wk = (const float*)d_in[2];
  const float* Wv = (const float*)d_in[3];
  const float* Wo = (const float*)d_in[4];
  char* ws = (char*)d_ws;
  unsigned short* xbf  = (unsigned short*)(ws + 0);          // 33554432 B
  unsigned short* wqkv = (unsigned short*)(ws + 33554432);   // 6291456 B
  unsigned short* wo   = (unsigned short*)(ws + 39845888);   // 2097152 B
  unsigned short* q    = (unsigned short*)(ws + 41943040);   // 33554432 B
  unsigned short* k    = (unsigned short*)(ws + 75497472);   // 33554432 B
  unsigned short* v    = (unsigned short*)(ws + 109051904);  // 33554432 B
  unsigned short* attn = (unsigned short*)(ws + 142606336);  // 33554432 B
  unsigned short* Spref= (unsigned short*)(ws + 176160768);  // 16777216 B (in-place scanned)
  float* zbuf          = (float*)(ws + 192937984);           // 524288 B
  float* zpref         = (float*)(ws + 193462272);           // 524288 B

  cast_all<<<10240, 256, 0, stream>>>(x, Wq, Wk, Wv, Wo, xbf, wqkv, wo);
  gemm_bt<1><<<3072, 256, 0, stream>>>(xbf, wqkv, nullptr, q, k, v, 1024, 3072, 24);
  chunk_state<<<2048, 256, 0, stream>>>(k, v, Spref, zbuf);
  scan_all<<<528, 256, 0, stream>>>(Spref, zbuf, zpref);
  chunk_out<<<2048, 256, 0, stream>>>(q, k, v, Spref, zpref, attn);
  gemm_bt<0><<<1024, 256, 0, stream>>>(attn, wo, d_out, nullptr, nullptr, nullptr, 1024, 1024, 8);
}